// Round 8
// baseline (210.396 us; speedup 1.0000x reference)
//
#include <hip/hip_runtime.h>
#include <hip/hip_bf16.h>

typedef unsigned short u16;
typedef short bf16x8 __attribute__((ext_vector_type(8)));
typedef float f32x4 __attribute__((ext_vector_type(4)));

#define NROWS 8192
#define EMBD  1140
#define FDIM  3968   // 32*124 = 62*64
#define N1R   1000
#define N1P   1024
#define N2R   100
#define N2P   128
#define DG    512

__device__ inline u16 f2b(float f) {
  __hip_bfloat16 h = __float2bfloat16(f);
  return *reinterpret_cast<u16*>(&h);
}

__device__ inline float b2f(u16 u) {
  unsigned v = (unsigned)u << 16;
  union { unsigned u; float f; } c;
  c.u = v;
  return c.f;
}

__device__ inline float tanh_fast(float x) {
  float ax = fabsf(x);
  float t = __expf(-2.f * ax);
  float r = (1.f - t) / (1.f + t);
  return x < 0.f ? -r : r;
}

// lrelu(a+b) on bf16x8 pairs -> bf16x8 (identical math/rounding to old conv_combine)
__device__ inline bf16x8 combine8(bf16x8 a, bf16x8 b) {
  bf16x8 o;
#pragma unroll
  for (int j = 0; j < 8; ++j) {
    float v = b2f((u16)a[j]) + b2f((u16)b[j]);
    v = v > 0.f ? v : 0.01f * v;
    o[j] = (short)f2b(v);
  }
  return o;
}

// async global->LDS, 16B per lane; LDS dest = wave-uniform base + lane*16
__device__ inline void gld16(const void* g, void* l) {
  __builtin_amdgcn_global_load_lds(
      (const __attribute__((address_space(1))) unsigned int*)g,
      (__attribute__((address_space(3))) unsigned int*)l, 16, 0, 0);
}

// ---------------- prep: ALL weight conversions + separable-conv precompute ----------------
// blocks [0,1984): W1; [1984,2048): W2; [2048,2080): Wg; [2080,2112): We; [2112,2756): precomp_ab.
__global__ __launch_bounds__(256) void prep_kernel(
    const float* __restrict__ W1, const float* __restrict__ W2,
    const float* __restrict__ Wg, const float* __restrict__ We,
    const float* __restrict__ H_emb, const float* __restrict__ conv_w,
    const float* __restrict__ conv_b,
    u16* __restrict__ W1bf, u16* __restrict__ W2bf,
    u16* __restrict__ Wgbf, u16* __restrict__ Webf,
    u16* __restrict__ Abuf, u16* __restrict__ Bbuf) {
  const int b = blockIdx.x;
  const int t = threadIdx.x;
  if (b < 2112) {
    const float* src;
    u16* dst;
    int row, c8, realRow, realCol;
    if (b < 1984) {            // W1: 1024x3968
      int id = b * 256 + t;
      row = id / 496; c8 = (id - row * 496) * 8;
      src = W1 + (size_t)row * FDIM + c8;
      dst = W1bf + (size_t)row * FDIM + c8;
      realRow = N1R; realCol = FDIM;
    } else if (b < 2048) {     // W2: 128x1024, realK=1000
      int id = (b - 1984) * 256 + t;
      row = id >> 7; c8 = (id & 127) * 8;
      src = W2 + (size_t)row * N1R + c8;
      dst = W2bf + (size_t)row * N1P + c8;
      realRow = N2R; realCol = N1R;
    } else if (b < 2080) {     // Wg: 128x512
      int id = (b - 2048) * 256 + t;
      row = id >> 6; c8 = (id & 63) * 8;
      src = Wg + (size_t)row * DG + c8;
      dst = Wgbf + (size_t)row * DG + c8;
      realRow = N2R; realCol = DG;
    } else {                   // We: 128x512
      int id = (b - 2080) * 256 + t;
      row = id >> 6; c8 = (id & 63) * 8;
      src = We + (size_t)row * DG + c8;
      dst = Webf + (size_t)row * DG + c8;
      realRow = N2R; realCol = DG;
    }
    bf16x8 o = (bf16x8){0, 0, 0, 0, 0, 0, 0, 0};
    if (row < realRow && c8 < realCol) {
#pragma unroll
      for (int j = 0; j < 8; ++j) o[j] = (short)f2b(src[j]);
    }
    *(bf16x8*)dst = o;
    return;
  }
  // ---- precomp_ab segment (bf16 output) ----
  __shared__ float se[EMBD];
  __shared__ float sw[32 * 25];
  __shared__ float sb[32];
  const int eb = b - 2112;   // 0..643
  bool isA = eb < 240;
  const float* emb = H_emb + (size_t)eb * EMBD;
  u16* outp = isA ? (Abuf + (size_t)eb * FDIM) : (Bbuf + (size_t)(eb - 240) * FDIM);
  for (int i = t; i < EMBD; i += 256) se[i] = emb[i];
  int kh = isA ? 0 : 1;
  for (int i = t; i < 800; i += 256) {
    int o = i / 25, kw = i - o * 25;
    sw[i] = conv_w[o * 50 + kh * 25 + kw];
  }
  if (t < 32) sb[t] = isA ? conv_b[t] : 0.f;
  __syncthreads();
  for (int f = t; f < FDIM; f += 256) {
    int o = f / 124, wpos = f - o * 124;
    const float* e = se + wpos * 9;
    const float* wp = sw + o * 25;
    float acc = sb[o];
#pragma unroll
    for (int kw = 0; kw < 25; ++kw) acc += wp[kw] * e[kw];
    outp[f] = f2b(acc);
  }
}

// ---------------- FC1 fused: A = lrelu(Abuf[xi]+Bbuf[yi]) staged in-kernel ----------------
// 128x128 tile, BK=64, double-buffered. B-side: global_load_lds (pre-swizzled source).
// A-side: reg-staged gather from L2-resident panels — issue loads for tile kt+1 BEFORE
// compute(kt), combine+ds_write AFTER (T14 split); ds_write goes to the swizzled slot
// directly (lane*16B contiguous => conflict-free). Same XOR invariant both operands:
// LDS[row][u] = PANEL[row][u ^ (row&7)].
__global__ __launch_bounds__(256) void fc1_kernel(
    const u16* __restrict__ Abuf, const u16* __restrict__ Bbuf,
    const int* __restrict__ xi, const int* __restrict__ yi,
    const u16* __restrict__ B,
    const float* __restrict__ bias, int realN,
    u16* __restrict__ C, int K, int ldc, int nTilesX) {
  const int nwg = gridDim.x;
  const int cpx = nwg >> 3;
  const int bid = blockIdx.x;
  const int wg = (bid & 7) * cpx + (bid >> 3);   // XCD gets contiguous wg chunk
  const int tm = (wg / nTilesX) * 128;
  const int tn = (wg % nTilesX) * 128;

  __shared__ u16 As[2][8192];   // [buf][128 rows x 64 cols]
  __shared__ u16 Bs[2][8192];
  const int t = threadIdx.x;
  const int lane = t & 63;
  const int w = t >> 6;
  const int wr = (w >> 1) * 64, wc = (w & 1) * 64;
  const int fr = lane & 15;
  const int kg = lane >> 4;

  const int srow = lane >> 3;                 // 0..7 within 8-row chunk
  const int su = ((lane & 7) ^ srow) * 8;     // pre-swizzled panel/global u16-col
  const u16* pA[4];                           // A-source: Abuf[xi[row]] gather
  const u16* pB[4];                           // A-source: Bbuf[yi[row]] gather
  const u16* gB[4];                           // B-operand: W1bf rows (gld16)
  int ldsOff[4];
#pragma unroll
  for (int i = 0; i < 4; ++i) {
    const int c = w + i * 4;                  // chunk 0..15, 8 rows each
    const int row = tm + c * 8 + srow;
    pA[i] = Abuf + (size_t)xi[row] * FDIM + su;
    pB[i] = Bbuf + (size_t)yi[row] * FDIM + su;
    gB[i] = B + (size_t)(tn + c * 8 + srow) * K + su;
    ldsOff[i] = c * 512;                      // u16 offset of chunk
  }

  f32x4 acc[4][4];
#pragma unroll
  for (int m = 0; m < 4; ++m)
#pragma unroll
    for (int n = 0; n < 4; ++n) acc[m][n] = (f32x4){0.f, 0.f, 0.f, 0.f};

  const int nk = K >> 6;   // BK=64
  bf16x8 ra[4], rb[4];
  // prologue: stage tile 0
#pragma unroll
  for (int i = 0; i < 4; ++i) {
    ra[i] = *(const bf16x8*)(pA[i]);
    rb[i] = *(const bf16x8*)(pB[i]);
    gld16(gB[i], &Bs[0][ldsOff[i]]);
  }
#pragma unroll
  for (int i = 0; i < 4; ++i)
    *(bf16x8*)(&As[0][ldsOff[i] + lane * 8]) = combine8(ra[i], rb[i]);
  __syncthreads();   // drains vmcnt + lgkm

  for (int kt = 0; kt < nk; ++kt) {
    const int cb = kt & 1;
    if (kt + 1 < nk) {   // issue next-tile loads FIRST (latency hides under compute)
      const int ko = (kt + 1) << 6;
#pragma unroll
      for (int i = 0; i < 4; ++i) {
        ra[i] = *(const bf16x8*)(pA[i] + ko);
        rb[i] = *(const bf16x8*)(pB[i] + ko);
        gld16(gB[i] + ko, &Bs[cb ^ 1][ldsOff[i]]);
      }
    }
    __builtin_amdgcn_sched_barrier(0);   // pin: load-issue stays above compute
#pragma unroll
    for (int ks = 0; ks < 2; ++ks) {
      const int un = ((ks * 4 + kg) ^ (fr & 7)) << 4;   // byte offset of swizzled 16B unit
      bf16x8 af[4], bff[4];
#pragma unroll
      for (int m = 0; m < 4; ++m)
        af[m] = *(const bf16x8*)((const char*)As[cb] + (wr + m * 16 + fr) * 128 + un);
#pragma unroll
      for (int n = 0; n < 4; ++n)
        bff[n] = *(const bf16x8*)((const char*)Bs[cb] + (wc + n * 16 + fr) * 128 + un);
#pragma unroll
      for (int m = 0; m < 4; ++m)
#pragma unroll
        for (int n = 0; n < 4; ++n)
          acc[m][n] = __builtin_amdgcn_mfma_f32_16x16x32_bf16(af[m], bff[n], acc[m][n], 0, 0, 0);
    }
    if (kt + 1 < nk) {   // write-late: combine lands in the freed buffer
#pragma unroll
      for (int i = 0; i < 4; ++i)
        *(bf16x8*)(&As[cb ^ 1][ldsOff[i] + lane * 8]) = combine8(ra[i], rb[i]);
    }
    __syncthreads();   // waits prefetch (vmcnt+lgkm) + guards buffer swap
  }

  // epilogue: C/D layout col=lane&15, row=(lane>>4)*4+j  [m89/m91]
#pragma unroll
  for (int n = 0; n < 4; ++n) {
    int col = tn + wc + n * 16 + fr;
    float bv = (col < realN) ? bias[col] : 0.f;
#pragma unroll
    for (int m = 0; m < 4; ++m) {
#pragma unroll
      for (int j = 0; j < 4; ++j) {
        int row = tm + wr + m * 16 + kg * 4 + j;
        float v = acc[m][n][j] + bv;
        v = v > 0.f ? v : 0.01f * v;
        C[(size_t)row * ldc + col] = f2b(v);
      }
    }
  }
}

// ---------------- fused tail: barrier-free GEMM sections, 512 blocks ----------------
__global__ __launch_bounds__(256) void tail_kernel(
    const u16* __restrict__ hfc1, const u16* __restrict__ W2bf, const float* __restrict__ b2,
    const float* __restrict__ ldg, const float* __restrict__ lde,
    const u16* __restrict__ Wgbf, const float* __restrict__ bg,
    const u16* __restrict__ Webf, const float* __restrict__ be,
    float* __restrict__ out0, float* __restrict__ out1) {
  __shared__ float H16[N2P][16];     // [col][row] hfc2 tile
  __shared__ float dpart[2][4][16];  // [sec][wave][row] partial dots
  __shared__ float wt[2][16];        // softmax weights

  const int tm = blockIdx.x * 16;
  const int t = threadIdx.x;
  const int lane = t & 63;
  const int w = t >> 6;
  const int fr = lane & 15;
  const int kg = lane >> 4;
  const int n0 = w * 2;              // this wave's two 16-col n-tiles

  // ---- FC2: hfc2 = lrelu(hfc1 @ W2^T + b2), K=1024, barrier-free ----
  {
    f32x4 a0 = (f32x4){0.f, 0.f, 0.f, 0.f}, a1 = a0;
    const u16* Ap = hfc1 + (size_t)(tm + fr) * N1P + kg * 8;
    const u16* B0 = W2bf + (size_t)(n0 * 16 + fr) * N1P + kg * 8;
    const u16* B1 = B0 + (size_t)16 * N1P;
#pragma unroll 8
    for (int kt = 0; kt < N1P / 32; ++kt) {
      bf16x8 af = *(const bf16x8*)(Ap + kt * 32);
      bf16x8 f0 = *(const bf16x8*)(B0 + kt * 32);
      bf16x8 f1 = *(const bf16x8*)(B1 + kt * 32);
      a0 = __builtin_amdgcn_mfma_f32_16x16x32_bf16(af, f0, a0, 0, 0, 0);
      a1 = __builtin_amdgcn_mfma_f32_16x16x32_bf16(af, f1, a1, 0, 0, 0);
    }
#pragma unroll
    for (int n = 0; n < 2; ++n) {
      int col = (n0 + n) * 16 + fr;
      float bv = (col < N2R) ? b2[col] : 0.f;
      f32x4 v = n == 0 ? a0 : a1;
      f32x4 o;
#pragma unroll
      for (int j = 0; j < 4; ++j) {
        float x = v[j] + bv;
        o[j] = x > 0.f ? x : 0.01f * x;
      }
      *(f32x4*)&H16[col][kg * 4] = o;
    }
  }
  __syncthreads();

  // ---- G/E gate sections: tanh(ld @ W^T + b), dot with H16 ----
#pragma unroll 1
  for (int sec = 0; sec < 2; ++sec) {
    const float* ld = sec == 0 ? ldg : lde;
    const u16* Wb = sec == 0 ? Wgbf : Webf;
    const float* bb = sec == 0 ? bg : be;

    f32x4 a0 = (f32x4){0.f, 0.f, 0.f, 0.f}, a1 = a0;
    const float* Ap = ld + (size_t)(tm + fr) * DG + kg * 8;
    const u16* B0 = Wb + (size_t)(n0 * 16 + fr) * DG + kg * 8;
    const u16* B1 = B0 + (size_t)16 * DG;
#pragma unroll 4
    for (int kt = 0; kt < DG / 32; ++kt) {
      float4 v0 = *(const float4*)(Ap + kt * 32);
      float4 v1 = *(const float4*)(Ap + kt * 32 + 4);
      bf16x8 af;
      af[0] = (short)f2b(v0.x); af[1] = (short)f2b(v0.y);
      af[2] = (short)f2b(v0.z); af[3] = (short)f2b(v0.w);
      af[4] = (short)f2b(v1.x); af[5] = (short)f2b(v1.y);
      af[6] = (short)f2b(v1.z); af[7] = (short)f2b(v1.w);
      bf16x8 f0 = *(const bf16x8*)(B0 + kt * 32);
      bf16x8 f1 = *(const bf16x8*)(B1 + kt * 32);
      a0 = __builtin_amdgcn_mfma_f32_16x16x32_bf16(af, f0, a0, 0, 0, 0);
      a1 = __builtin_amdgcn_mfma_f32_16x16x32_bf16(af, f1, a1, 0, 0, 0);
    }
    float dv[4] = {0.f, 0.f, 0.f, 0.f};
#pragma unroll
    for (int n = 0; n < 2; ++n) {
      int col = (n0 + n) * 16 + fr;
      float bv = (col < N2R) ? bb[col] : 0.f;
      f32x4 v = n == 0 ? a0 : a1;
      f32x4 h = *(const f32x4*)&H16[col][kg * 4];
#pragma unroll
      for (int j = 0; j < 4; ++j)
        dv[j] += tanh_fast(v[j] + bv) * h[j];
    }
#pragma unroll
    for (int j = 0; j < 4; ++j) {
      float v = dv[j];
      v += __shfl_xor(v, 1);
      v += __shfl_xor(v, 2);
      v += __shfl_xor(v, 4);
      v += __shfl_xor(v, 8);
      dv[j] = v;
    }
    if (fr == 0) {
#pragma unroll
      for (int j = 0; j < 4; ++j) dpart[sec][w][kg * 4 + j] = dv[j];
    }
  }
  __syncthreads();

  // ---- softmax per row ----
  if (t < 16) {
    float ag = dpart[0][0][t] + dpart[0][1][t] + dpart[0][2][t] + dpart[0][3][t];
    float ae = dpart[1][0][t] + dpart[1][1][t] + dpart[1][2][t] + dpart[1][3][t];
    float mm = fmaxf(ag, ae);
    float eg = __expf(ag - mm), eo = __expf(ae - mm);
    float inv = 1.f / (eg + eo);
    wt[0][t] = eg * inv;
    wt[1][t] = eo * inv;
  }
  __syncthreads();

  // ---- scale + write both outputs (coalesced float4) ----
  for (int i = t; i < 16 * (DG / 4); i += 256) {
    int r = i >> 7, c = i & 127;
    float w0 = wt[0][r], w1 = wt[1][r];
    size_t off = (size_t)(tm + r) * DG + c * 4;
    float4 a = *(const float4*)(ldg + off);
    a.x *= w0; a.y *= w0; a.z *= w0; a.w *= w0;
    *(float4*)(out0 + off) = a;
    float4 b = *(const float4*)(lde + off);
    b.x *= w1; b.y *= w1; b.z *= w1; b.w *= w1;
    *(float4*)(out1 + off) = b;
  }
}

extern "C" void kernel_launch(void* const* d_in, const int* in_sizes, int n_in,
                              void* d_out, int out_size, void* d_ws, size_t ws_size,
                              hipStream_t stream) {
  const float* ld_gcn = (const float*)d_in[0];
  const float* ld_enc = (const float*)d_in[1];
  const int*   xi     = (const int*)d_in[2];
  const int*   yi     = (const int*)d_in[3];
  const float* H_emb  = (const float*)d_in[4];
  const float* conv_w = (const float*)d_in[5];
  const float* conv_b = (const float*)d_in[6];
  const float* W1     = (const float*)d_in[7];
  const float* b1     = (const float*)d_in[8];
  const float* W2     = (const float*)d_in[9];
  const float* b2     = (const float*)d_in[10];
  const float* Wg     = (const float*)d_in[11];
  const float* bg     = (const float*)d_in[12];
  const float* We     = (const float*)d_in[13];
  const float* be     = (const float*)d_in[14];

  char* ws = (char*)d_ws;
  size_t off = 0;
  auto alloc = [&](size_t bytes) -> void* {
    void* p = ws + off;
    off = (off + bytes + 255) & ~(size_t)255;
    return p;
  };
  u16* Abuf = (u16*)alloc(240ull * FDIM * 2);
  u16* Bbuf = (u16*)alloc(404ull * FDIM * 2);
  u16* W1bf = (u16*)alloc((size_t)N1P * FDIM * 2);
  u16* W2bf = (u16*)alloc((size_t)N2P * N1P * 2);
  u16* Wgbf = (u16*)alloc((size_t)N2P * DG * 2);
  u16* Webf = (u16*)alloc((size_t)N2P * DG * 2);
  u16* hfc1 = (u16*)alloc((size_t)NROWS * N1P * 2);
  if (ws_size < off) return;  // ~31 MB needed

  prep_kernel<<<2756, 256, 0, stream>>>(W1, W2, Wg, We, H_emb, conv_w, conv_b,
                                        W1bf, W2bf, Wgbf, Webf, Abuf, Bbuf);

  fc1_kernel<<<dim3((NROWS / 128) * (N1P / 128)), 256, 0, stream>>>(
      Abuf, Bbuf, xi, yi, W1bf, b1, N1R, hfc1, FDIM, N1P, N1P / 128);

  float* out0 = (float*)d_out;
  float* out1 = out0 + (size_t)NROWS * DG;
  tail_kernel<<<NROWS / 16, 256, 0, stream>>>(
      hfc1, W2bf, b2, ld_gcn, ld_enc, Wgbf, bg, Webf, be, out0, out1);
}

// Round 9
// 187.749 us; speedup vs baseline: 1.1206x; 1.1206x over previous
//
#include <hip/hip_runtime.h>
#include <hip/hip_bf16.h>

typedef unsigned short u16;
typedef short bf16x8 __attribute__((ext_vector_type(8)));
typedef float f32x4 __attribute__((ext_vector_type(4)));

#define NROWS 8192
#define EMBD  1140
#define FDIM  3968   // 32*124 = 62*64
#define N1R   1000
#define N1P   1024
#define N2R   100
#define N2P   128
#define DG    512

__device__ inline u16 f2b(float f) {
  __hip_bfloat16 h = __float2bfloat16(f);
  return *reinterpret_cast<u16*>(&h);
}

__device__ inline float b2f(u16 u) {
  unsigned v = (unsigned)u << 16;
  union { unsigned u; float f; } c;
  c.u = v;
  return c.f;
}

__device__ inline float tanh_fast(float x) {
  float ax = fabsf(x);
  float t = __expf(-2.f * ax);
  float r = (1.f - t) / (1.f + t);
  return x < 0.f ? -r : r;
}

// async global->LDS, 16B per lane; LDS dest = wave-uniform base + lane*16
__device__ inline void gld16(const void* g, void* l) {
  __builtin_amdgcn_global_load_lds(
      (const __attribute__((address_space(1))) unsigned int*)g,
      (__attribute__((address_space(3))) unsigned int*)l, 16, 0, 0);
}

// ---------------- prep: ALL weight conversions + separable-conv precompute ----------------
__global__ __launch_bounds__(256) void prep_kernel(
    const float* __restrict__ W1, const float* __restrict__ W2,
    const float* __restrict__ Wg, const float* __restrict__ We,
    const float* __restrict__ H_emb, const float* __restrict__ conv_w,
    const float* __restrict__ conv_b,
    u16* __restrict__ W1bf, u16* __restrict__ W2bf,
    u16* __restrict__ Wgbf, u16* __restrict__ Webf,
    u16* __restrict__ Abuf, u16* __restrict__ Bbuf) {
  const int b = blockIdx.x;
  const int t = threadIdx.x;
  if (b < 2112) {
    const float* src;
    u16* dst;
    int row, c8, realRow, realCol;
    if (b < 1984) {            // W1: 1024x3968
      int id = b * 256 + t;
      row = id / 496; c8 = (id - row * 496) * 8;
      src = W1 + (size_t)row * FDIM + c8;
      dst = W1bf + (size_t)row * FDIM + c8;
      realRow = N1R; realCol = FDIM;
    } else if (b < 2048) {     // W2: 128x1024, realK=1000
      int id = (b - 1984) * 256 + t;
      row = id >> 7; c8 = (id & 127) * 8;
      src = W2 + (size_t)row * N1R + c8;
      dst = W2bf + (size_t)row * N1P + c8;
      realRow = N2R; realCol = N1R;
    } else if (b < 2080) {     // Wg: 128x512
      int id = (b - 2048) * 256 + t;
      row = id >> 6; c8 = (id & 63) * 8;
      src = Wg + (size_t)row * DG + c8;
      dst = Wgbf + (size_t)row * DG + c8;
      realRow = N2R; realCol = DG;
    } else {                   // We: 128x512
      int id = (b - 2080) * 256 + t;
      row = id >> 6; c8 = (id & 63) * 8;
      src = We + (size_t)row * DG + c8;
      dst = Webf + (size_t)row * DG + c8;
      realRow = N2R; realCol = DG;
    }
    bf16x8 o = (bf16x8){0, 0, 0, 0, 0, 0, 0, 0};
    if (row < realRow && c8 < realCol) {
#pragma unroll
      for (int j = 0; j < 8; ++j) o[j] = (short)f2b(src[j]);
    }
    *(bf16x8*)dst = o;
    return;
  }
  // ---- precomp_ab segment (bf16 output) ----
  __shared__ float se[EMBD];
  __shared__ float sw[32 * 25];
  __shared__ float sb[32];
  const int eb = b - 2112;   // 0..643
  bool isA = eb < 240;
  const float* emb = H_emb + (size_t)eb * EMBD;
  u16* outp = isA ? (Abuf + (size_t)eb * FDIM) : (Bbuf + (size_t)(eb - 240) * FDIM);
  for (int i = t; i < EMBD; i += 256) se[i] = emb[i];
  int kh = isA ? 0 : 1;
  for (int i = t; i < 800; i += 256) {
    int o = i / 25, kw = i - o * 25;
    sw[i] = conv_w[o * 50 + kh * 25 + kw];
  }
  if (t < 32) sb[t] = isA ? conv_b[t] : 0.f;
  __syncthreads();
  for (int f = t; f < FDIM; f += 256) {
    int o = f / 124, wpos = f - o * 124;
    const float* e = se + wpos * 9;
    const float* wp = sw + o * 25;
    float acc = sb[o];
#pragma unroll
    for (int kw = 0; kw < 25; ++kw) acc += wp[kw] * e[kw];
    outp[f] = f2b(acc);
  }
}

// c[r][f] = lrelu(A[x[r]][f] + B[y[r]][f])  -> bf16  (A/B bf16: L2-resident panels)
__global__ __launch_bounds__(256) void conv_combine_kernel(
    const u16* __restrict__ Abuf, const u16* __restrict__ Bbuf,
    const int* __restrict__ xi, const int* __restrict__ yi, u16* __restrict__ cbf) {
  int r = blockIdx.x;
  const bf16x8* pa = (const bf16x8*)(Abuf + (size_t)xi[r] * FDIM);
  const bf16x8* pb = (const bf16x8*)(Bbuf + (size_t)yi[r] * FDIM);
  bf16x8* out = (bf16x8*)(cbf + (size_t)r * FDIM);
  for (int i = threadIdx.x; i < FDIM / 8; i += 256) {
    bf16x8 a = pa[i], b = pb[i];
    bf16x8 o;
#pragma unroll
    for (int j = 0; j < 8; ++j) {
      float v = b2f((u16)a[j]) + b2f((u16)b[j]);
      v = v > 0.f ? v : 0.01f * v;
      o[j] = (short)f2b(v);
    }
    out[i] = o;
  }
}

// ---------------- FC1: 128x128 tile, BK=64, double-buffered gld (round-7 proven) ----------------
// Swizzle (rule 21, both sides): LDS[row][u16unit u] = Global[row][u ^ (row&7)].
__global__ __launch_bounds__(256) void fc1_kernel(
    const u16* __restrict__ A, const u16* __restrict__ B,
    const float* __restrict__ bias, int realN,
    u16* __restrict__ C, int K, int ldc, int nTilesX) {
  const int nwg = gridDim.x;
  const int cpx = nwg >> 3;
  const int bid = blockIdx.x;
  const int wg = (bid & 7) * cpx + (bid >> 3);   // XCD gets contiguous wg chunk
  const int tm = (wg / nTilesX) * 128;
  const int tn = (wg % nTilesX) * 128;

  __shared__ u16 As[2][8192];   // [buf][128 rows x 64 cols]
  __shared__ u16 Bs[2][8192];
  const int t = threadIdx.x;
  const int lane = t & 63;
  const int w = t >> 6;
  const int wr = (w >> 1) * 64, wc = (w & 1) * 64;
  const int fr = lane & 15;
  const int kg = lane >> 4;

  const int srow = lane >> 3;                 // 0..7 within 8-row chunk
  const int su = ((lane & 7) ^ srow) * 8;     // pre-swizzled global u16-col
  const u16* gA[4];
  const u16* gB[4];
  int ldsOff[4];
#pragma unroll
  for (int i = 0; i < 4; ++i) {
    const int c = w + i * 4;                  // chunk 0..15, 8 rows each
    gA[i] = A + (size_t)(tm + c * 8 + srow) * K + su;
    gB[i] = B + (size_t)(tn + c * 8 + srow) * K + su;
    ldsOff[i] = c * 512;                      // u16 offset of chunk
  }

  f32x4 acc[4][4];
#pragma unroll
  for (int m = 0; m < 4; ++m)
#pragma unroll
    for (int n = 0; n < 4; ++n) acc[m][n] = (f32x4){0.f, 0.f, 0.f, 0.f};

  const int nk = K >> 6;   // BK=64
  // prologue: stage tile 0 into buf 0
#pragma unroll
  for (int i = 0; i < 4; ++i) {
    gld16(gA[i], &As[0][ldsOff[i]]);
    gld16(gB[i], &Bs[0][ldsOff[i]]);
  }
  __syncthreads();   // drains vmcnt

  for (int kt = 0; kt < nk; ++kt) {
    const int cb = kt & 1;
    if (kt + 1 < nk) {   // issue next-tile loads FIRST (latency hides under compute)
      const int ko = (kt + 1) << 6;
#pragma unroll
      for (int i = 0; i < 4; ++i) {
        gld16(gA[i] + ko, &As[cb ^ 1][ldsOff[i]]);
        gld16(gB[i] + ko, &Bs[cb ^ 1][ldsOff[i]]);
      }
    }
    __builtin_amdgcn_sched_barrier(0);   // pin: stage-issue stays above compute
#pragma unroll
    for (int ks = 0; ks < 2; ++ks) {
      const int un = ((ks * 4 + kg) ^ (fr & 7)) << 4;   // byte offset of swizzled 16B unit
      bf16x8 af[4], bff[4];
#pragma unroll
      for (int m = 0; m < 4; ++m)
        af[m] = *(const bf16x8*)((const char*)As[cb] + (wr + m * 16 + fr) * 128 + un);
#pragma unroll
      for (int n = 0; n < 4; ++n)
        bff[n] = *(const bf16x8*)((const char*)Bs[cb] + (wc + n * 16 + fr) * 128 + un);
#pragma unroll
      for (int m = 0; m < 4; ++m)
#pragma unroll
        for (int n = 0; n < 4; ++n)
          acc[m][n] = __builtin_amdgcn_mfma_f32_16x16x32_bf16(af[m], bff[n], acc[m][n], 0, 0, 0);
    }
    __syncthreads();   // waits this iter's prefetch (vmcnt) + guards buffer swap
  }

  // epilogue: C/D layout col=lane&15, row=(lane>>4)*4+j  [m89/m91]
#pragma unroll
  for (int n = 0; n < 4; ++n) {
    int col = tn + wc + n * 16 + fr;
    float bv = (col < realN) ? bias[col] : 0.f;
#pragma unroll
    for (int m = 0; m < 4; ++m) {
#pragma unroll
      for (int j = 0; j < 4; ++j) {
        int row = tm + wr + m * 16 + kg * 4 + j;
        float v = acc[m][n][j] + bv;
        v = v > 0.f ? v : 0.01f * v;
        C[(size_t)row * ldc + col] = f2b(v);
      }
    }
  }
}

// ---------------- tail v3: 8 waves, parallel gate sections, dual-accumulator chains ----------------
// Block = 16 rows. FC2: wave w owns n-tile w (1 MFMA chain pair, even/odd kt).
// Gates: waves 0-3 = gcn, waves 4-7 = enc, each wave 2 n-tiles, 4 indep chains.
__global__ __launch_bounds__(512) void tail_kernel(
    const u16* __restrict__ hfc1, const u16* __restrict__ W2bf, const float* __restrict__ b2,
    const float* __restrict__ ldg, const float* __restrict__ lde,
    const u16* __restrict__ Wgbf, const float* __restrict__ bg,
    const u16* __restrict__ Webf, const float* __restrict__ be,
    float* __restrict__ out0, float* __restrict__ out1) {
  __shared__ float H16[N2P][16];     // [col][row] hfc2 tile
  __shared__ float dpart[2][4][16];  // [sec][wavegrp][row] partial dots
  __shared__ float wt[2][16];        // softmax weights

  const int tm = blockIdx.x * 16;
  const int t = threadIdx.x;
  const int lane = t & 63;
  const int w = t >> 6;              // 0..7
  const int fr = lane & 15;
  const int kg = lane >> 4;

  // ---- FC2: hfc2 = lrelu(hfc1 @ W2^T + b2), K=1024; wave w -> cols [w*16, w*16+16) ----
  {
    f32x4 ae = (f32x4){0.f, 0.f, 0.f, 0.f}, ao = ae;
    const u16* Ap = hfc1 + (size_t)(tm + fr) * N1P + kg * 8;
    const u16* Bp = W2bf + (size_t)(w * 16 + fr) * N1P + kg * 8;
#pragma unroll 4
    for (int k2 = 0; k2 < 16; ++k2) {
      bf16x8 af0 = *(const bf16x8*)(Ap + k2 * 64);
      bf16x8 f0  = *(const bf16x8*)(Bp + k2 * 64);
      bf16x8 af1 = *(const bf16x8*)(Ap + k2 * 64 + 32);
      bf16x8 f1  = *(const bf16x8*)(Bp + k2 * 64 + 32);
      ae = __builtin_amdgcn_mfma_f32_16x16x32_bf16(af0, f0, ae, 0, 0, 0);
      ao = __builtin_amdgcn_mfma_f32_16x16x32_bf16(af1, f1, ao, 0, 0, 0);
    }
    int col = w * 16 + fr;
    float bv = (col < N2R) ? b2[col] : 0.f;
    f32x4 o;
#pragma unroll
    for (int j = 0; j < 4; ++j) {
      float x = ae[j] + ao[j] + bv;
      o[j] = x > 0.f ? x : 0.01f * x;
    }
    *(f32x4*)&H16[col][kg * 4] = o;
  }
  __syncthreads();

  // ---- Gates (both sections concurrent): sec = w>>2; wave handles n-tiles (w&3)*2, +1 ----
  {
    const int sec = w >> 2;
    const float* ld = sec == 0 ? ldg : lde;
    const u16* Wb = sec == 0 ? Wgbf : Webf;
    const float* bb = sec == 0 ? bg : be;
    const int n0 = (w & 3) * 2;

    f32x4 a0e = (f32x4){0.f, 0.f, 0.f, 0.f}, a0o = a0e, a1e = a0e, a1o = a0e;
    const float* Ap = ld + (size_t)(tm + fr) * DG + kg * 8;
    const u16* B0 = Wb + (size_t)(n0 * 16 + fr) * DG + kg * 8;
    const u16* B1 = B0 + (size_t)16 * DG;
#pragma unroll 4
    for (int k2 = 0; k2 < 8; ++k2) {
      float4 v0 = *(const float4*)(Ap + k2 * 64);
      float4 v1 = *(const float4*)(Ap + k2 * 64 + 4);
      float4 v2 = *(const float4*)(Ap + k2 * 64 + 32);
      float4 v3 = *(const float4*)(Ap + k2 * 64 + 36);
      bf16x8 af0, af1;
      af0[0] = (short)f2b(v0.x); af0[1] = (short)f2b(v0.y);
      af0[2] = (short)f2b(v0.z); af0[3] = (short)f2b(v0.w);
      af0[4] = (short)f2b(v1.x); af0[5] = (short)f2b(v1.y);
      af0[6] = (short)f2b(v1.z); af0[7] = (short)f2b(v1.w);
      af1[0] = (short)f2b(v2.x); af1[1] = (short)f2b(v2.y);
      af1[2] = (short)f2b(v2.z); af1[3] = (short)f2b(v2.w);
      af1[4] = (short)f2b(v3.x); af1[5] = (short)f2b(v3.y);
      af1[6] = (short)f2b(v3.z); af1[7] = (short)f2b(v3.w);
      bf16x8 f00 = *(const bf16x8*)(B0 + k2 * 64);
      bf16x8 f10 = *(const bf16x8*)(B1 + k2 * 64);
      bf16x8 f01 = *(const bf16x8*)(B0 + k2 * 64 + 32);
      bf16x8 f11 = *(const bf16x8*)(B1 + k2 * 64 + 32);
      a0e = __builtin_amdgcn_mfma_f32_16x16x32_bf16(af0, f00, a0e, 0, 0, 0);
      a1e = __builtin_amdgcn_mfma_f32_16x16x32_bf16(af0, f10, a1e, 0, 0, 0);
      a0o = __builtin_amdgcn_mfma_f32_16x16x32_bf16(af1, f01, a0o, 0, 0, 0);
      a1o = __builtin_amdgcn_mfma_f32_16x16x32_bf16(af1, f11, a1o, 0, 0, 0);
    }
    float dv[4] = {0.f, 0.f, 0.f, 0.f};
#pragma unroll
    for (int n = 0; n < 2; ++n) {
      int col = (n0 + n) * 16 + fr;
      float bv = (col < N2R) ? bb[col] : 0.f;
      f32x4 s;
#pragma unroll
      for (int j = 0; j < 4; ++j)
        s[j] = (n == 0 ? a0e[j] + a0o[j] : a1e[j] + a1o[j]) + bv;
      f32x4 h = *(const f32x4*)&H16[col][kg * 4];
#pragma unroll
      for (int j = 0; j < 4; ++j)
        dv[j] += tanh_fast(s[j]) * h[j];
    }
#pragma unroll
    for (int j = 0; j < 4; ++j) {
      float v = dv[j];
      v += __shfl_xor(v, 1);
      v += __shfl_xor(v, 2);
      v += __shfl_xor(v, 4);
      v += __shfl_xor(v, 8);
      dv[j] = v;
    }
    if (fr == 0) {
#pragma unroll
      for (int j = 0; j < 4; ++j) dpart[sec][w & 3][kg * 4 + j] = dv[j];
    }
  }
  __syncthreads();

  // ---- softmax per row ----
  if (t < 16) {
    float ag = dpart[0][0][t] + dpart[0][1][t] + dpart[0][2][t] + dpart[0][3][t];
    float ae = dpart[1][0][t] + dpart[1][1][t] + dpart[1][2][t] + dpart[1][3][t];
    float mm = fmaxf(ag, ae);
    float eg = __expf(ag - mm), eo = __expf(ae - mm);
    float inv = 1.f / (eg + eo);
    wt[0][t] = eg * inv;
    wt[1][t] = eo * inv;
  }
  __syncthreads();

  // ---- scale + write both outputs (coalesced float4, 512 threads) ----
  for (int i = t; i < 16 * (DG / 4); i += 512) {
    int r = i >> 7, c = i & 127;
    float w0 = wt[0][r], w1 = wt[1][r];
    size_t off = (size_t)(tm + r) * DG + c * 4;
    float4 a = *(const float4*)(ldg + off);
    a.x *= w0; a.y *= w0; a.z *= w0; a.w *= w0;
    *(float4*)(out0 + off) = a;
    float4 b = *(const float4*)(lde + off);
    b.x *= w1; b.y *= w1; b.z *= w1; b.w *= w1;
    *(float4*)(out1 + off) = b;
  }
}

extern "C" void kernel_launch(void* const* d_in, const int* in_sizes, int n_in,
                              void* d_out, int out_size, void* d_ws, size_t ws_size,
                              hipStream_t stream) {
  const float* ld_gcn = (const float*)d_in[0];
  const float* ld_enc = (const float*)d_in[1];
  const int*   xi     = (const int*)d_in[2];
  const int*   yi     = (const int*)d_in[3];
  const float* H_emb  = (const float*)d_in[4];
  const float* conv_w = (const float*)d_in[5];
  const float* conv_b = (const float*)d_in[6];
  const float* W1     = (const float*)d_in[7];
  const float* b1     = (const float*)d_in[8];
  const float* W2     = (const float*)d_in[9];
  const float* b2     = (const float*)d_in[10];
  const float* Wg     = (const float*)d_in[11];
  const float* bg     = (const float*)d_in[12];
  const float* We     = (const float*)d_in[13];
  const float* be     = (const float*)d_in[14];

  char* ws = (char*)d_ws;
  size_t off = 0;
  auto alloc = [&](size_t bytes) -> void* {
    void* p = ws + off;
    off = (off + bytes + 255) & ~(size_t)255;
    return p;
  };
  u16* Abuf = (u16*)alloc(240ull * FDIM * 2);
  u16* Bbuf = (u16*)alloc(404ull * FDIM * 2);
  u16* cbf  = (u16*)alloc((size_t)NROWS * FDIM * 2);
  u16* W1bf = (u16*)alloc((size_t)N1P * FDIM * 2);
  u16* W2bf = (u16*)alloc((size_t)N2P * N1P * 2);
  u16* Wgbf = (u16*)alloc((size_t)N2P * DG * 2);
  u16* Webf = (u16*)alloc((size_t)N2P * DG * 2);
  u16* hfc1 = (u16*)alloc((size_t)NROWS * N1P * 2);
  if (ws_size < off) return;  // ~96 MB needed

  prep_kernel<<<2756, 256, 0, stream>>>(W1, W2, Wg, We, H_emb, conv_w, conv_b,
                                        W1bf, W2bf, Wgbf, Webf, Abuf, Bbuf);
  conv_combine_kernel<<<NROWS, 256, 0, stream>>>(Abuf, Bbuf, xi, yi, cbf);

  fc1_kernel<<<dim3((NROWS / 128) * (N1P / 128)), 256, 0, stream>>>(
      cbf, W1bf, b1, N1R, hfc1, FDIM, N1P, N1P / 128);

  float* out0 = (float*)d_out;
  float* out1 = out0 + (size_t)NROWS * DG;
  tail_kernel<<<NROWS / 16, 512, 0, stream>>>(
      hfc1, W2bf, b2, ld_gcn, ld_enc, Wgbf, bg, Webf, be, out0, out1);
}

// Round 10
// 184.192 us; speedup vs baseline: 1.1423x; 1.0193x over previous
//
#include <hip/hip_runtime.h>
#include <hip/hip_bf16.h>

typedef unsigned short u16;
typedef short bf16x8 __attribute__((ext_vector_type(8)));
typedef float f32x4 __attribute__((ext_vector_type(4)));

#define NROWS 8192
#define EMBD  1140
#define FDIM  3968   // 32*124 = 62*64
#define N1R   1000
#define N1P   1024
#define N2R   100
#define N2P   128
#define DG    512

__device__ inline u16 f2b(float f) {
  __hip_bfloat16 h = __float2bfloat16(f);
  return *reinterpret_cast<u16*>(&h);
}

__device__ inline float b2f(u16 u) {
  unsigned v = (unsigned)u << 16;
  union { unsigned u; float f; } c;
  c.u = v;
  return c.f;
}

__device__ inline float tanh_fast(float x) {
  float ax = fabsf(x);
  float t = __expf(-2.f * ax);
  float r = (1.f - t) / (1.f + t);
  return x < 0.f ? -r : r;
}

// async global->LDS, 16B per lane; LDS dest = wave-uniform base + lane*16
__device__ inline void gld16(const void* g, void* l) {
  __builtin_amdgcn_global_load_lds(
      (const __attribute__((address_space(1))) unsigned int*)g,
      (__attribute__((address_space(3))) unsigned int*)l, 16, 0, 0);
}

// ---------------- prep: ALL weight conversions + separable-conv precompute ----------------
__global__ __launch_bounds__(256) void prep_kernel(
    const float* __restrict__ W1, const float* __restrict__ W2,
    const float* __restrict__ Wg, const float* __restrict__ We,
    const float* __restrict__ H_emb, const float* __restrict__ conv_w,
    const float* __restrict__ conv_b,
    u16* __restrict__ W1bf, u16* __restrict__ W2bf,
    u16* __restrict__ Wgbf, u16* __restrict__ Webf,
    u16* __restrict__ Abuf, u16* __restrict__ Bbuf) {
  const int b = blockIdx.x;
  const int t = threadIdx.x;
  if (b < 2112) {
    const float* src;
    u16* dst;
    int row, c8, realRow, realCol;
    if (b < 1984) {            // W1: 1024x3968
      int id = b * 256 + t;
      row = id / 496; c8 = (id - row * 496) * 8;
      src = W1 + (size_t)row * FDIM + c8;
      dst = W1bf + (size_t)row * FDIM + c8;
      realRow = N1R; realCol = FDIM;
    } else if (b < 2048) {     // W2: 128x1024, realK=1000
      int id = (b - 1984) * 256 + t;
      row = id >> 7; c8 = (id & 127) * 8;
      src = W2 + (size_t)row * N1R + c8;
      dst = W2bf + (size_t)row * N1P + c8;
      realRow = N2R; realCol = N1R;
    } else if (b < 2080) {     // Wg: 128x512
      int id = (b - 2048) * 256 + t;
      row = id >> 6; c8 = (id & 63) * 8;
      src = Wg + (size_t)row * DG + c8;
      dst = Wgbf + (size_t)row * DG + c8;
      realRow = N2R; realCol = DG;
    } else {                   // We: 128x512
      int id = (b - 2080) * 256 + t;
      row = id >> 6; c8 = (id & 63) * 8;
      src = We + (size_t)row * DG + c8;
      dst = Webf + (size_t)row * DG + c8;
      realRow = N2R; realCol = DG;
    }
    bf16x8 o = (bf16x8){0, 0, 0, 0, 0, 0, 0, 0};
    if (row < realRow && c8 < realCol) {
#pragma unroll
      for (int j = 0; j < 8; ++j) o[j] = (short)f2b(src[j]);
    }
    *(bf16x8*)dst = o;
    return;
  }
  // ---- precomp_ab segment (bf16 output) ----
  __shared__ float se[EMBD];
  __shared__ float sw[32 * 25];
  __shared__ float sb[32];
  const int eb = b - 2112;   // 0..643
  bool isA = eb < 240;
  const float* emb = H_emb + (size_t)eb * EMBD;
  u16* outp = isA ? (Abuf + (size_t)eb * FDIM) : (Bbuf + (size_t)(eb - 240) * FDIM);
  for (int i = t; i < EMBD; i += 256) se[i] = emb[i];
  int kh = isA ? 0 : 1;
  for (int i = t; i < 800; i += 256) {
    int o = i / 25, kw = i - o * 25;
    sw[i] = conv_w[o * 50 + kh * 25 + kw];
  }
  if (t < 32) sb[t] = isA ? conv_b[t] : 0.f;
  __syncthreads();
  for (int f = t; f < FDIM; f += 256) {
    int o = f / 124, wpos = f - o * 124;
    const float* e = se + wpos * 9;
    const float* wp = sw + o * 25;
    float acc = sb[o];
#pragma unroll
    for (int kw = 0; kw < 25; ++kw) acc += wp[kw] * e[kw];
    outp[f] = f2b(acc);
  }
}

// c[r][f] = lrelu(A[x[r]][f] + B[y[r]][f])  -> bf16  (A/B bf16: L2-resident panels)
__global__ __launch_bounds__(256) void conv_combine_kernel(
    const u16* __restrict__ Abuf, const u16* __restrict__ Bbuf,
    const int* __restrict__ xi, const int* __restrict__ yi, u16* __restrict__ cbf) {
  int r = blockIdx.x;
  const bf16x8* pa = (const bf16x8*)(Abuf + (size_t)xi[r] * FDIM);
  const bf16x8* pb = (const bf16x8*)(Bbuf + (size_t)yi[r] * FDIM);
  bf16x8* out = (bf16x8*)(cbf + (size_t)r * FDIM);
  for (int i = threadIdx.x; i < FDIM / 8; i += 256) {
    bf16x8 a = pa[i], b = pb[i];
    bf16x8 o;
#pragma unroll
    for (int j = 0; j < 8; ++j) {
      float v = b2f((u16)a[j]) + b2f((u16)b[j]);
      v = v > 0.f ? v : 0.01f * v;
      o[j] = (short)f2b(v);
    }
    out[i] = o;
  }
}

// ---------------- FC1: 128x128 tile, BK=64, double-buffered gld (round-7 proven) ----------------
// Swizzle (rule 21, both sides): LDS[row][u16unit u] = Global[row][u ^ (row&7)].
__global__ __launch_bounds__(256) void fc1_kernel(
    const u16* __restrict__ A, const u16* __restrict__ B,
    const float* __restrict__ bias, int realN,
    u16* __restrict__ C, int K, int ldc, int nTilesX) {
  const int nwg = gridDim.x;
  const int cpx = nwg >> 3;
  const int bid = blockIdx.x;
  const int wg = (bid & 7) * cpx + (bid >> 3);   // XCD gets contiguous wg chunk
  const int tm = (wg / nTilesX) * 128;
  const int tn = (wg % nTilesX) * 128;

  __shared__ u16 As[2][8192];   // [buf][128 rows x 64 cols]
  __shared__ u16 Bs[2][8192];
  const int t = threadIdx.x;
  const int lane = t & 63;
  const int w = t >> 6;
  const int wr = (w >> 1) * 64, wc = (w & 1) * 64;
  const int fr = lane & 15;
  const int kg = lane >> 4;

  const int srow = lane >> 3;                 // 0..7 within 8-row chunk
  const int su = ((lane & 7) ^ srow) * 8;     // pre-swizzled global u16-col
  const u16* gA[4];
  const u16* gB[4];
  int ldsOff[4];
#pragma unroll
  for (int i = 0; i < 4; ++i) {
    const int c = w + i * 4;                  // chunk 0..15, 8 rows each
    gA[i] = A + (size_t)(tm + c * 8 + srow) * K + su;
    gB[i] = B + (size_t)(tn + c * 8 + srow) * K + su;
    ldsOff[i] = c * 512;                      // u16 offset of chunk
  }

  f32x4 acc[4][4];
#pragma unroll
  for (int m = 0; m < 4; ++m)
#pragma unroll
    for (int n = 0; n < 4; ++n) acc[m][n] = (f32x4){0.f, 0.f, 0.f, 0.f};

  const int nk = K >> 6;   // BK=64
  // prologue: stage tile 0 into buf 0
#pragma unroll
  for (int i = 0; i < 4; ++i) {
    gld16(gA[i], &As[0][ldsOff[i]]);
    gld16(gB[i], &Bs[0][ldsOff[i]]);
  }
  __syncthreads();   // drains vmcnt

  for (int kt = 0; kt < nk; ++kt) {
    const int cb = kt & 1;
    if (kt + 1 < nk) {   // issue next-tile loads FIRST (latency hides under compute)
      const int ko = (kt + 1) << 6;
#pragma unroll
      for (int i = 0; i < 4; ++i) {
        gld16(gA[i] + ko, &As[cb ^ 1][ldsOff[i]]);
        gld16(gB[i] + ko, &Bs[cb ^ 1][ldsOff[i]]);
      }
    }
    __builtin_amdgcn_sched_barrier(0);   // pin: stage-issue stays above compute
#pragma unroll
    for (int ks = 0; ks < 2; ++ks) {
      const int un = ((ks * 4 + kg) ^ (fr & 7)) << 4;   // byte offset of swizzled 16B unit
      bf16x8 af[4], bff[4];
#pragma unroll
      for (int m = 0; m < 4; ++m)
        af[m] = *(const bf16x8*)((const char*)As[cb] + (wr + m * 16 + fr) * 128 + un);
#pragma unroll
      for (int n = 0; n < 4; ++n)
        bff[n] = *(const bf16x8*)((const char*)Bs[cb] + (wc + n * 16 + fr) * 128 + un);
#pragma unroll
      for (int m = 0; m < 4; ++m)
#pragma unroll
        for (int n = 0; n < 4; ++n)
          acc[m][n] = __builtin_amdgcn_mfma_f32_16x16x32_bf16(af[m], bff[n], acc[m][n], 0, 0, 0);
    }
    __syncthreads();   // waits this iter's prefetch (vmcnt) + guards buffer swap
  }

  // epilogue: C/D layout col=lane&15, row=(lane>>4)*4+j  [m89/m91]
#pragma unroll
  for (int n = 0; n < 4; ++n) {
    int col = tn + wc + n * 16 + fr;
    float bv = (col < realN) ? bias[col] : 0.f;
#pragma unroll
    for (int m = 0; m < 4; ++m) {
#pragma unroll
      for (int j = 0; j < 4; ++j) {
        int row = tm + wr + m * 16 + kg * 4 + j;
        float v = acc[m][n][j] + bv;
        v = v > 0.f ? v : 0.01f * v;
        C[(size_t)row * ldc + col] = f2b(v);
      }
    }
  }
}

// ---------------- tail v4: v2 structure + 4-chain even/odd ILP (single-variable change) ----------------
// Block = 16 rows, 4 waves (256 thr), 512 blocks; wave w owns cols [w*32, w*32+32).
// FC2 and each gate section use 4 independent accumulator chains (even/odd K split).
__global__ __launch_bounds__(256) void tail_kernel(
    const u16* __restrict__ hfc1, const u16* __restrict__ W2bf, const float* __restrict__ b2,
    const float* __restrict__ ldg, const float* __restrict__ lde,
    const u16* __restrict__ Wgbf, const float* __restrict__ bg,
    const u16* __restrict__ Webf, const float* __restrict__ be,
    float* __restrict__ out0, float* __restrict__ out1) {
  __shared__ float H16[N2P][16];     // [col][row] hfc2 tile
  __shared__ float dpart[2][4][16];  // [sec][wave][row] partial dots
  __shared__ float wt[2][16];        // softmax weights

  const int tm = blockIdx.x * 16;
  const int t = threadIdx.x;
  const int lane = t & 63;
  const int w = t >> 6;
  const int fr = lane & 15;
  const int kg = lane >> 4;
  const int n0 = w * 2;              // this wave's two 16-col n-tiles

  // ---- FC2: hfc2 = lrelu(hfc1 @ W2^T + b2), K=1024, 4 indep chains ----
  {
    f32x4 a0e = (f32x4){0.f, 0.f, 0.f, 0.f}, a0o = a0e, a1e = a0e, a1o = a0e;
    const u16* Ap = hfc1 + (size_t)(tm + fr) * N1P + kg * 8;
    const u16* B0 = W2bf + (size_t)(n0 * 16 + fr) * N1P + kg * 8;
    const u16* B1 = B0 + (size_t)16 * N1P;
#pragma unroll 4
    for (int k2 = 0; k2 < 16; ++k2) {
      bf16x8 afe = *(const bf16x8*)(Ap + k2 * 64);
      bf16x8 afo = *(const bf16x8*)(Ap + k2 * 64 + 32);
      bf16x8 f0e = *(const bf16x8*)(B0 + k2 * 64);
      bf16x8 f0o = *(const bf16x8*)(B0 + k2 * 64 + 32);
      bf16x8 f1e = *(const bf16x8*)(B1 + k2 * 64);
      bf16x8 f1o = *(const bf16x8*)(B1 + k2 * 64 + 32);
      a0e = __builtin_amdgcn_mfma_f32_16x16x32_bf16(afe, f0e, a0e, 0, 0, 0);
      a1e = __builtin_amdgcn_mfma_f32_16x16x32_bf16(afe, f1e, a1e, 0, 0, 0);
      a0o = __builtin_amdgcn_mfma_f32_16x16x32_bf16(afo, f0o, a0o, 0, 0, 0);
      a1o = __builtin_amdgcn_mfma_f32_16x16x32_bf16(afo, f1o, a1o, 0, 0, 0);
    }
#pragma unroll
    for (int n = 0; n < 2; ++n) {
      int col = (n0 + n) * 16 + fr;
      float bv = (col < N2R) ? b2[col] : 0.f;
      f32x4 o;
#pragma unroll
      for (int j = 0; j < 4; ++j) {
        float x = (n == 0 ? a0e[j] + a0o[j] : a1e[j] + a1o[j]) + bv;
        o[j] = x > 0.f ? x : 0.01f * x;
      }
      *(f32x4*)&H16[col][kg * 4] = o;
    }
  }
  __syncthreads();

  // ---- G/E gate sections (serial, as v2): tanh(ld @ W^T + b), dot with H16; 4 chains ----
#pragma unroll 1
  for (int sec = 0; sec < 2; ++sec) {
    const float* ld = sec == 0 ? ldg : lde;
    const u16* Wb = sec == 0 ? Wgbf : Webf;
    const float* bb = sec == 0 ? bg : be;

    f32x4 a0e = (f32x4){0.f, 0.f, 0.f, 0.f}, a0o = a0e, a1e = a0e, a1o = a0e;
    const float* Ap = ld + (size_t)(tm + fr) * DG + kg * 8;
    const u16* B0 = Wb + (size_t)(n0 * 16 + fr) * DG + kg * 8;
    const u16* B1 = B0 + (size_t)16 * DG;
#pragma unroll 2
    for (int k2 = 0; k2 < 8; ++k2) {
      float4 v0 = *(const float4*)(Ap + k2 * 64);
      float4 v1 = *(const float4*)(Ap + k2 * 64 + 4);
      float4 v2 = *(const float4*)(Ap + k2 * 64 + 32);
      float4 v3 = *(const float4*)(Ap + k2 * 64 + 36);
      bf16x8 afe, afo;
      afe[0] = (short)f2b(v0.x); afe[1] = (short)f2b(v0.y);
      afe[2] = (short)f2b(v0.z); afe[3] = (short)f2b(v0.w);
      afe[4] = (short)f2b(v1.x); afe[5] = (short)f2b(v1.y);
      afe[6] = (short)f2b(v1.z); afe[7] = (short)f2b(v1.w);
      afo[0] = (short)f2b(v2.x); afo[1] = (short)f2b(v2.y);
      afo[2] = (short)f2b(v2.z); afo[3] = (short)f2b(v2.w);
      afo[4] = (short)f2b(v3.x); afo[5] = (short)f2b(v3.y);
      afo[6] = (short)f2b(v3.z); afo[7] = (short)f2b(v3.w);
      bf16x8 f0e = *(const bf16x8*)(B0 + k2 * 64);
      bf16x8 f0o = *(const bf16x8*)(B0 + k2 * 64 + 32);
      bf16x8 f1e = *(const bf16x8*)(B1 + k2 * 64);
      bf16x8 f1o = *(const bf16x8*)(B1 + k2 * 64 + 32);
      a0e = __builtin_amdgcn_mfma_f32_16x16x32_bf16(afe, f0e, a0e, 0, 0, 0);
      a1e = __builtin_amdgcn_mfma_f32_16x16x32_bf16(afe, f1e, a1e, 0, 0, 0);
      a0o = __builtin_amdgcn_mfma_f32_16x16x32_bf16(afo, f0o, a0o, 0, 0, 0);
      a1o = __builtin_amdgcn_mfma_f32_16x16x32_bf16(afo, f1o, a1o, 0, 0, 0);
    }
    float dv[4] = {0.f, 0.f, 0.f, 0.f};
#pragma unroll
    for (int n = 0; n < 2; ++n) {
      int col = (n0 + n) * 16 + fr;
      float bv = (col < N2R) ? bb[col] : 0.f;
      f32x4 h = *(const f32x4*)&H16[col][kg * 4];
#pragma unroll
      for (int j = 0; j < 4; ++j) {
        float s = (n == 0 ? a0e[j] + a0o[j] : a1e[j] + a1o[j]) + bv;
        dv[j] += tanh_fast(s) * h[j];
      }
    }
#pragma unroll
    for (int j = 0; j < 4; ++j) {
      float v = dv[j];
      v += __shfl_xor(v, 1);
      v += __shfl_xor(v, 2);
      v += __shfl_xor(v, 4);
      v += __shfl_xor(v, 8);
      dv[j] = v;
    }
    if (fr == 0) {
#pragma unroll
      for (int j = 0; j < 4; ++j) dpart[sec][w][kg * 4 + j] = dv[j];
    }
  }
  __syncthreads();

  // ---- softmax per row ----
  if (t < 16) {
    float ag = dpart[0][0][t] + dpart[0][1][t] + dpart[0][2][t] + dpart[0][3][t];
    float ae = dpart[1][0][t] + dpart[1][1][t] + dpart[1][2][t] + dpart[1][3][t];
    float mm = fmaxf(ag, ae);
    float eg = __expf(ag - mm), eo = __expf(ae - mm);
    float inv = 1.f / (eg + eo);
    wt[0][t] = eg * inv;
    wt[1][t] = eo * inv;
  }
  __syncthreads();

  // ---- scale + write both outputs (coalesced float4) ----
  for (int i = t; i < 16 * (DG / 4); i += 256) {
    int r = i >> 7, c = i & 127;
    float w0 = wt[0][r], w1 = wt[1][r];
    size_t off = (size_t)(tm + r) * DG + c * 4;
    float4 a = *(const float4*)(ldg + off);
    a.x *= w0; a.y *= w0; a.z *= w0; a.w *= w0;
    *(float4*)(out0 + off) = a;
    float4 b = *(const float4*)(lde + off);
    b.x *= w1; b.y *= w1; b.z *= w1; b.w *= w1;
    *(float4*)(out1 + off) = b;
  }
}

extern "C" void kernel_launch(void* const* d_in, const int* in_sizes, int n_in,
                              void* d_out, int out_size, void* d_ws, size_t ws_size,
                              hipStream_t stream) {
  const float* ld_gcn = (const float*)d_in[0];
  const float* ld_enc = (const float*)d_in[1];
  const int*   xi     = (const int*)d_in[2];
  const int*   yi     = (const int*)d_in[3];
  const float* H_emb  = (const float*)d_in[4];
  const float* conv_w = (const float*)d_in[5];
  const float* conv_b = (const float*)d_in[6];
  const float* W1     = (const float*)d_in[7];
  const float* b1     = (const float*)d_in[8];
  const float* W2     = (const float*)d_in[9];
  const float* b2     = (const float*)d_in[10];
  const float* Wg     = (const float*)d_in[11];
  const float* bg     = (const float*)d_in[12];
  const float* We     = (const float*)d_in[13];
  const float* be     = (const float*)d_in[14];

  char* ws = (char*)d_ws;
  size_t off = 0;
  auto alloc = [&](size_t bytes) -> void* {
    void* p = ws + off;
    off = (off + bytes + 255) & ~(size_t)255;
    return p;
  };
  u16* Abuf = (u16*)alloc(240ull * FDIM * 2);
  u16* Bbuf = (u16*)alloc(404ull * FDIM * 2);
  u16* cbf  = (u16*)alloc((size_t)NROWS * FDIM * 2);
  u16* W1bf = (u16*)alloc((size_t)N1P * FDIM * 2);
  u16* W2bf = (u16*)alloc((size_t)N2P * N1P * 2);
  u16* Wgbf = (u16*)alloc((size_t)N2P * DG * 2);
  u16* Webf = (u16*)alloc((size_t)N2P * DG * 2);
  u16* hfc1 = (u16*)alloc((size_t)NROWS * N1P * 2);
  if (ws_size < off) return;  // ~96 MB needed

  prep_kernel<<<2756, 256, 0, stream>>>(W1, W2, Wg, We, H_emb, conv_w, conv_b,
                                        W1bf, W2bf, Wgbf, Webf, Abuf, Bbuf);
  conv_combine_kernel<<<NROWS, 256, 0, stream>>>(Abuf, Bbuf, xi, yi, cbf);

  fc1_kernel<<<dim3((NROWS / 128) * (N1P / 128)), 256, 0, stream>>>(
      cbf, W1bf, b1, N1R, hfc1, FDIM, N1P, N1P / 128);

  float* out0 = (float*)d_out;
  float* out1 = out0 + (size_t)NROWS * DG;
  tail_kernel<<<NROWS / 16, 256, 0, stream>>>(
      hfc1, W2bf, b2, ld_gcn, ld_enc, Wgbf, bg, Webf, be, out0, out1);
}